// Round 11
// baseline (568.375 us; speedup 1.0000x reference)
//
#include <hip/hip_runtime.h>

typedef unsigned short ushortT;
typedef unsigned int uintT;
typedef __attribute__((ext_vector_type(8))) short bf16x8;
typedef __attribute__((ext_vector_type(16))) float f32x16;
typedef __attribute__((ext_vector_type(4))) unsigned short ushort4v;

constexpr int T_LEN = 2048;
constexpr int BSZ_C = 2;
constexpr int E_C   = 1024;
constexpr int H_C   = 16;
constexpr int NH    = 32;    // BSZ*H
constexpr int E3    = 3072;
constexpr int M_C   = T_LEN * BSZ_C;   // 4096

static __device__ inline ushortT f2bf(float f) {
    union { float f; uintT u; } v; v.f = f;
    uintT u = v.u;
    return (ushortT)((u + 0x7fffu + ((u >> 16) & 1u)) >> 16);
}
static __device__ inline f32x16 mfma_bf16(bf16x8 a, bf16x8 b, f32x16 c) {
    return __builtin_amdgcn_mfma_f32_32x32x16_bf16(a, b, c, 0, 0, 0);
}
// async global->LDS, 16B per lane; dest = wave-uniform base + lane*16
static __device__ inline void gload_lds16(const ushortT* g, ushortT* l) {
    __builtin_amdgcn_global_load_lds(
        (const __attribute__((address_space(1))) void*)g,
        (__attribute__((address_space(3))) void*)l, 16, 0, 0);
}

// ---------------------------------------------------------------------------
// pack3: fused f32 -> bf16 for query / W_in / W_out (one launch)
// ---------------------------------------------------------------------------
constexpr int Q4C  = M_C * E_C / 4;        // 1048576
constexpr int WI4C = E3 * E_C / 4;         // 786432
constexpr int WO4C = E_C * E_C / 4;        // 262144

__global__ __launch_bounds__(256) void pack3(const float* __restrict__ query,
                                             const float* __restrict__ W_in,
                                             const float* __restrict__ W_out,
                                             ushortT* __restrict__ qh,
                                             ushortT* __restrict__ Wih,
                                             ushortT* __restrict__ Woh)
{
    const int total = Q4C + WI4C + WO4C;
    const int stride = gridDim.x * 256;
    for (int i = blockIdx.x * 256 + threadIdx.x; i < total; i += stride) {
        const float4* src;
        ushortT* dst;
        int j;
        if (i < Q4C)              { src = (const float4*)query; dst = qh;  j = i; }
        else if (i < Q4C + WI4C)  { src = (const float4*)W_in;  dst = Wih; j = i - Q4C; }
        else                      { src = (const float4*)W_out; dst = Woh; j = i - Q4C - WI4C; }
        float4 v = src[j];
        ushort4v h;
        h.x = f2bf(v.x); h.y = f2bf(v.y); h.z = f2bf(v.z); h.w = f2bf(v.w);
        *(ushort4v*)(dst + (size_t)j * 4) = h;
    }
}

// ---------------------------------------------------------------------------
// gemm_bf16_qkv: qkv = query_h @ W_in_h^T + b (single bf16 product), BK=64,
// global_load_lds staging with both-sides XOR swizzle.
// Epilogue: q_h/k_h coalesced 2B stores; v_t via LDS transpose ([c][m] pad
// 136) -> 8B stores of 4 consecutive t.
// ---------------------------------------------------------------------------
__global__ __launch_bounds__(256) void gemm_bf16_qkv(const ushortT* __restrict__ Ah,
                                                     const ushortT* __restrict__ Bh,
                                                     const float* __restrict__ bias,
                                                     ushortT* __restrict__ qh_o,
                                                     ushortT* __restrict__ kh_o,
                                                     ushortT* __restrict__ vt_o)
{
    const int K = E_C;
    __shared__ ushortT SH[17408];    // union: As=SH[0:8192),Bs=[8192:16384); epilogue vt[c][136]

    const int tid = threadIdx.x;
    const int bm = blockIdx.y * 128, bn = blockIdx.x * 128;
    const int w  = tid >> 6;
    const int wm = w >> 1, wn = w & 1;
    const int l  = tid & 63;
    const int lc = l & 31, hi = l >> 5;

    f32x16 acc[2][2];
    #pragma unroll
    for (int a = 0; a < 2; a++)
        #pragma unroll
        for (int b = 0; b < 2; b++)
            #pragma unroll
            for (int r = 0; r < 16; r++) acc[a][b][r] = 0.f;

    for (int k0 = 0; k0 < K; k0 += 64) {
        #pragma unroll
        for (int it = 0; it < 4; it++) {
            int idx = it * 256 + (w << 6) + l;      // 16B-unit index, 0..1023
            int row = idx >> 3;
            int cs  = (idx & 7) ^ (row & 7);        // pre-swizzled source col
            size_t goff = (size_t)row * K + k0 + cs * 8;
            int lbase = (it * 256 + (w << 6)) * 8;  // wave-uniform, ushorts
            gload_lds16(Ah + (size_t)bm * K + goff, SH + lbase);
            gload_lds16(Bh + (size_t)bn * K + goff, SH + 8192 + lbase);
        }
        __syncthreads();

        #pragma unroll
        for (int ks = 0; ks < 4; ks++) {
            bf16x8 af[2], bfr[2];
            #pragma unroll
            for (int ms = 0; ms < 2; ms++) {
                int r = wm * 64 + ms * 32 + lc;
                af[ms] = *(const bf16x8*)(&SH[r * 64 + ((((ks << 1) + hi) ^ (r & 7)) << 3)]);
            }
            #pragma unroll
            for (int ns = 0; ns < 2; ns++) {
                int r = wn * 64 + ns * 32 + lc;
                bfr[ns] = *(const bf16x8*)(&SH[8192 + r * 64 + ((((ks << 1) + hi) ^ (r & 7)) << 3)]);
            }
            #pragma unroll
            for (int ms = 0; ms < 2; ms++)
                #pragma unroll
                for (int ns = 0; ns < 2; ns++)
                    acc[ms][ns] = mfma_bf16(af[ms], bfr[ns], acc[ms][ns]);
        }
        __syncthreads();
    }

    const bool is_v = (bn >= 2048);   // 128-aligned tiles: whole block one part
    if (is_v) {
        #pragma unroll
        for (int ms = 0; ms < 2; ms++)
            #pragma unroll
            for (int ns = 0; ns < 2; ns++) {
                int c = wn * 64 + ns * 32 + lc;
                float bcol = bias[bn + c];
                #pragma unroll
                for (int r = 0; r < 16; r++) {
                    int m = wm * 64 + ms * 32 + (r & 3) + 8 * (r >> 2) + 4 * hi;
                    SH[c * 136 + m] = f2bf(acc[ms][ns][r] + bcol);
                }
            }
        __syncthreads();
        int c    = tid >> 1;          // 0..127
        int half = tid & 1;
        int dd = c & 63, hh2 = c >> 6;
        int hh = ((bn - 2048) >> 6) + hh2;
        size_t tb = (size_t)(bm >> 1) + 32 * half;
        ushortT* d0 = vt_o + ((size_t)(hh)        * 64 + dd) * T_LEN + tb;  // b=0
        ushortT* d1 = vt_o + ((size_t)(H_C + hh)  * 64 + dd) * T_LEN + tb;  // b=1
        #pragma unroll
        for (int k = 0; k < 8; k++) {
            int m0 = 64 * half + 8 * k;
            ushort4v e0, e1;
            #pragma unroll
            for (int jj = 0; jj < 4; jj++) {
                e0[jj] = SH[c * 136 + m0 + 2 * jj];
                e1[jj] = SH[c * 136 + m0 + 2 * jj + 1];
            }
            *(ushort4v*)(d0 + 4 * k) = e0;
            *(ushort4v*)(d1 + 4 * k) = e1;
        }
    } else {
        #pragma unroll
        for (int ms = 0; ms < 2; ms++)
            #pragma unroll
            for (int ns = 0; ns < 2; ns++) {
                int col = bn + wn * 64 + ns * 32 + lc;
                float bcol = bias[col];
                ushortT* dst = (col < 1024) ? qh_o : kh_o;
                int cc = col & 1023, hh = cc >> 6, dd = cc & 63;
                #pragma unroll
                for (int r = 0; r < 16; r++) {
                    int row = bm + wm * 64 + ms * 32 + (r & 3) + 8 * (r >> 2) + 4 * hi;
                    int t = row >> 1, bb = row & 1;
                    int nhead = bb * H_C + hh;
                    dst[((size_t)nhead * T_LEN + t) * 64 + dd] = f2bf(acc[ms][ns][r] + bcol);
                }
            }
    }
}

// ---------------------------------------------------------------------------
// gemm_bf16_out: out = a_hi @ Woh^T + b_out, f32 nontemporal out. BK=64.
// ---------------------------------------------------------------------------
__global__ __launch_bounds__(256) void gemm_bf16_out(const ushortT* __restrict__ Ah,
                                                     const ushortT* __restrict__ Bh,
                                                     const float* __restrict__ bias,
                                                     float* __restrict__ Cf)
{
    const int K = E_C, N = E_C;
    __shared__ ushortT As[128][64];
    __shared__ ushortT Bs[128][64];

    const int tid = threadIdx.x;
    const int bm = blockIdx.y * 128, bn = blockIdx.x * 128;
    const int w  = tid >> 6;
    const int wm = w >> 1, wn = w & 1;
    const int l  = tid & 63;
    const int lc = l & 31, hi = l >> 5;

    f32x16 acc[2][2];
    #pragma unroll
    for (int a = 0; a < 2; a++)
        #pragma unroll
        for (int b = 0; b < 2; b++)
            #pragma unroll
            for (int r = 0; r < 16; r++) acc[a][b][r] = 0.f;

    for (int k0 = 0; k0 < K; k0 += 64) {
        #pragma unroll
        for (int it = 0; it < 4; it++) {
            int idx = it * 256 + (w << 6) + l;
            int row = idx >> 3;
            int cs  = (idx & 7) ^ (row & 7);
            size_t goff = (size_t)row * K + k0 + cs * 8;
            int lbase = (it * 256 + (w << 6)) * 8;
            gload_lds16(Ah + (size_t)bm * K + goff, &As[0][0] + lbase);
            gload_lds16(Bh + (size_t)bn * K + goff, &Bs[0][0] + lbase);
        }
        __syncthreads();

        #pragma unroll
        for (int ks = 0; ks < 4; ks++) {
            bf16x8 af[2], bfr[2];
            #pragma unroll
            for (int ms = 0; ms < 2; ms++) {
                int r = wm * 64 + ms * 32 + lc;
                af[ms] = *(const bf16x8*)(&As[r][(((ks << 1) + hi) ^ (r & 7)) << 3]);
            }
            #pragma unroll
            for (int ns = 0; ns < 2; ns++) {
                int r = wn * 64 + ns * 32 + lc;
                bfr[ns] = *(const bf16x8*)(&Bs[r][(((ks << 1) + hi) ^ (r & 7)) << 3]);
            }
            #pragma unroll
            for (int ms = 0; ms < 2; ms++)
                #pragma unroll
                for (int ns = 0; ns < 2; ns++)
                    acc[ms][ns] = mfma_bf16(af[ms], bfr[ns], acc[ms][ns]);
        }
        __syncthreads();
    }

    #pragma unroll
    for (int ms = 0; ms < 2; ms++)
        #pragma unroll
        for (int ns = 0; ns < 2; ns++)
            #pragma unroll
            for (int r = 0; r < 16; r++) {
                int row = bm + wm * 64 + ms * 32 + (r & 3) + 8 * (r >> 2) + 4 * hi;
                int col = bn + wn * 64 + ns * 32 + lc;
                __builtin_nontemporal_store(acc[ms][ns][r] + bias[col],
                                            &Cf[(size_t)row * N + col]);
            }
}

// ---------------------------------------------------------------------------
// attn_mfma (R5/R6 v1 structure + exp2 fold): block = (head n, 128 q-rows),
// 256 threads = 4 waves, wave-private, zero barriers.
// ---------------------------------------------------------------------------
__global__ __launch_bounds__(256) void attn_mfma(const ushortT* __restrict__ q_h,
                                                 const ushortT* __restrict__ k_h,
                                                 const ushortT* __restrict__ v_t,
                                                 float* __restrict__ p_out,
                                                 ushortT* __restrict__ a_hi)
{
    __shared__ ushortT plds[4][32][64];   // per-wave P tile, XOR-swizzled

    const int n = blockIdx.x;
    const int b = n >> 4, h = n & 15;
    const int t0 = blockIdx.y * 128;
    const int tid = threadIdx.x;
    const int w = tid >> 6, l = tid & 63;
    const int lc = l & 31, hi = l >> 5;
    const int trow_base = t0 + w * 32;

    const ushortT* qb = q_h + ((size_t)n * T_LEN + trow_base) * 64;
    const ushortT* kb = k_h + (size_t)n * T_LEN * 64;
    const ushortT* vb = v_t + (size_t)n * 64 * T_LEN;

    bf16x8 qf[4];
    #pragma unroll
    for (int ks = 0; ks < 4; ks++)
        qf[ks] = *(const bf16x8*)(qb + (size_t)lc * 64 + ks * 16 + hi * 8);

    const float K2 = 0.18033688011112042f;   // (1/8) * log2(e)

    // ---- pass A: row sums ----
    float sum[16];
    #pragma unroll
    for (int r = 0; r < 16; r++) sum[r] = 0.f;

    for (int s0 = 0; s0 < T_LEN; s0 += 32) {
        const ushortT* kr = kb + (size_t)(s0 + lc) * 64 + hi * 8;
        f32x16 c;
        #pragma unroll
        for (int r = 0; r < 16; r++) c[r] = 0.f;
        #pragma unroll
        for (int ks = 0; ks < 4; ks++)
            c = mfma_bf16(qf[ks], *(const bf16x8*)(kr + ks * 16), c);
        #pragma unroll
        for (int r = 0; r < 16; r++) sum[r] += __builtin_amdgcn_exp2f(c[r] * K2);
    }
    #pragma unroll
    for (int r = 0; r < 16; r++) {
        float s = sum[r];
        s += __shfl_xor(s, 1, 64);
        s += __shfl_xor(s, 2, 64);
        s += __shfl_xor(s, 4, 64);
        s += __shfl_xor(s, 8, 64);
        s += __shfl_xor(s, 16, 64);
        sum[r] = 1.0f / s;    // inv
    }

    // ---- pass B ----
    f32x16 o0, o1;
    #pragma unroll
    for (int r = 0; r < 16; r++) { o0[r] = 0.f; o1[r] = 0.f; }
    char* plbase = (char*)&plds[w][0][0];

    for (int s0 = 0; s0 < T_LEN; s0 += 32) {
        const ushortT* kr = kb + (size_t)(s0 + lc) * 64 + hi * 8;
        f32x16 c;
        #pragma unroll
        for (int r = 0; r < 16; r++) c[r] = 0.f;
        #pragma unroll
        for (int ks = 0; ks < 4; ks++)
            c = mfma_bf16(qf[ks], *(const bf16x8*)(kr + ks * 16), c);

        float pv[16];
        #pragma unroll
        for (int r = 0; r < 16; r++) pv[r] = __builtin_amdgcn_exp2f(c[r] * K2) * sum[r];

        size_t pbase = ((size_t)n * T_LEN) * T_LEN + s0 + lc;
        #pragma unroll
        for (int r = 0; r < 16; r++) {
            int t = trow_base + (r & 3) + 8 * (r >> 2) + 4 * hi;
            __builtin_nontemporal_store(pv[r], &p_out[pbase + (size_t)t * T_LEN]);
        }
        #pragma unroll
        for (int r = 0; r < 16; r++) {
            int row = (r & 3) + 8 * (r >> 2) + 4 * hi;
            int byte = row * 128 + ((lc * 2) ^ ((row & 7) << 4));
            *(ushortT*)(plbase + byte) = f2bf(pv[r]);
        }
        bf16x8 pa[2];
        #pragma unroll
        for (int sh = 0; sh < 2; sh++) {
            int S = (hi * 8 + sh * 16) * 2;
            int byte = lc * 128 + (S ^ ((lc & 7) << 4));
            pa[sh] = *(const bf16x8*)(plbase + byte);
        }
        #pragma unroll
        for (int sh = 0; sh < 2; sh++) {
            bf16x8 v0 = *(const bf16x8*)(vb + (size_t)(lc) * T_LEN + s0 + sh * 16 + hi * 8);
            bf16x8 v1 = *(const bf16x8*)(vb + (size_t)(32 + lc) * T_LEN + s0 + sh * 16 + hi * 8);
            o0 = mfma_bf16(pa[sh], v0, o0);
            o1 = mfma_bf16(pa[sh], v1, o1);
        }
    }

    // ---- write attn bf16 (already normalized; fed to out-projection) ----
    #pragma unroll
    for (int r = 0; r < 16; r++) {
        int t = trow_base + (r & 3) + 8 * (r >> 2) + 4 * hi;
        size_t m = (size_t)t * BSZ_C + b;
        size_t base = m * 1024 + h * 64;
        a_hi[base + lc]      = f2bf(o0[r]);
        a_hi[base + 32 + lc] = f2bf(o1[r]);
    }
}

// ---------------------------------------------------------------------------
// MEASUREMENT ROUND: every kernel launched TWICE (all are idempotent).
// S = sum(kernel times) = dur_R11 - dur_R6(293.9) - ~12us (4 extra gaps);
// OH = 293.9 - S - gaps. Decides R12: fusion (OH-dominant) vs kernel work
// (S-dominant).
// ---------------------------------------------------------------------------
extern "C" void kernel_launch(void* const* d_in, const int* in_sizes, int n_in,
                              void* d_out, int out_size, void* d_ws, size_t ws_size,
                              hipStream_t stream) {
    const float* query = (const float*)d_in[0];
    // d_in[1]/d_in[2] unused (reference derives q,k,v all from `query`)
    const float* W_in  = (const float*)d_in[3];
    const float* b_in  = (const float*)d_in[4];
    const float* W_out = (const float*)d_in[5];
    const float* b_out = (const float*)d_in[6];

    float* out   = (float*)d_out;
    float* p_out = out + (size_t)T_LEN * BSZ_C * E_C;

    char* ws = (char*)d_ws;
    ushortT* qh   = (ushortT*)(ws + 0);          // 8 MiB  query bf16
    ushortT* Wih  = (ushortT*)(ws + 8388608);    // 6 MiB  W_in bf16
    ushortT* Woh  = (ushortT*)(ws + 14680064);   // 2 MiB  W_out bf16
    ushortT* q_h  = (ushortT*)(ws + 16777216);   // 8 MiB
    ushortT* k_h  = (ushortT*)(ws + 25165824);   // 8 MiB
    ushortT* v_t  = (ushortT*)(ws + 33554432);   // 8 MiB
    ushortT* a_hi = (ushortT*)(ws + 41943040);   // 8 MiB (end 50331648)

    for (int rep = 0; rep < 2; rep++)
        pack3<<<dim3(2048), dim3(256), 0, stream>>>(query, W_in, W_out, qh, Wih, Woh);

    for (int rep = 0; rep < 2; rep++)
        gemm_bf16_qkv<<<dim3(E3 / 128, M_C / 128), dim3(256), 0, stream>>>(
            qh, Wih, b_in, q_h, k_h, v_t);

    for (int rep = 0; rep < 2; rep++)
        attn_mfma<<<dim3(NH, T_LEN / 128), dim3(256), 0, stream>>>(
            q_h, k_h, v_t, p_out, a_hi);

    for (int rep = 0; rep < 2; rep++)
        gemm_bf16_out<<<dim3(E_C / 128, M_C / 128), dim3(256), 0, stream>>>(
            a_hi, Woh, b_out, out);
}

// Round 13
// 285.959 us; speedup vs baseline: 1.9876x; 1.9876x over previous
//
#include <hip/hip_runtime.h>

typedef unsigned short ushortT;
typedef unsigned int uintT;
typedef __attribute__((ext_vector_type(8))) short bf16x8;
typedef __attribute__((ext_vector_type(16))) float f32x16;
typedef __attribute__((ext_vector_type(8))) unsigned short ushort8v;
typedef __attribute__((ext_vector_type(4))) unsigned short ushort4v;
typedef __attribute__((ext_vector_type(2))) unsigned short ushort2v;

constexpr int T_LEN = 2048;
constexpr int BSZ_C = 2;
constexpr int E_C   = 1024;
constexpr int H_C   = 16;
constexpr int NH    = 32;    // BSZ*H
constexpr int E3    = 3072;
constexpr int M_C   = T_LEN * BSZ_C;   // 4096

static __device__ inline ushortT f2bf(float f) {
    union { float f; uintT u; } v; v.f = f;
    uintT u = v.u;
    return (ushortT)((u + 0x7fffu + ((u >> 16) & 1u)) >> 16);
}
static __device__ inline f32x16 mfma_bf16(bf16x8 a, bf16x8 b, f32x16 c) {
    return __builtin_amdgcn_mfma_f32_32x32x16_bf16(a, b, c, 0, 0, 0);
}
// async global->LDS, 16B per lane; dest = wave-uniform base + lane*16
static __device__ inline void gload_lds16(const ushortT* g, ushortT* l) {
    __builtin_amdgcn_global_load_lds(
        (const __attribute__((address_space(1))) void*)g,
        (__attribute__((address_space(3))) void*)l, 16, 0, 0);
}

// ---------------------------------------------------------------------------
// pack3: fused f32 -> bf16 for query / W_in / W_out (one launch)
// ---------------------------------------------------------------------------
constexpr int Q4C  = M_C * E_C / 4;        // 1048576
constexpr int WI4C = E3 * E_C / 4;         // 786432
constexpr int WO4C = E_C * E_C / 4;        // 262144

__global__ __launch_bounds__(256) void pack3(const float* __restrict__ query,
                                             const float* __restrict__ W_in,
                                             const float* __restrict__ W_out,
                                             ushortT* __restrict__ qh,
                                             ushortT* __restrict__ Wih,
                                             ushortT* __restrict__ Woh)
{
    const int total = Q4C + WI4C + WO4C;
    const int stride = gridDim.x * 256;
    for (int i = blockIdx.x * 256 + threadIdx.x; i < total; i += stride) {
        const float4* src;
        ushortT* dst;
        int j;
        if (i < Q4C)              { src = (const float4*)query; dst = qh;  j = i; }
        else if (i < Q4C + WI4C)  { src = (const float4*)W_in;  dst = Wih; j = i - Q4C; }
        else                      { src = (const float4*)W_out; dst = Woh; j = i - Q4C - WI4C; }
        float4 v = src[j];
        ushort4v h;
        h.x = f2bf(v.x); h.y = f2bf(v.y); h.z = f2bf(v.z); h.w = f2bf(v.w);
        *(ushort4v*)(dst + (size_t)j * 4) = h;
    }
}

// ---------------------------------------------------------------------------
// gemm_bf16_qkv: qkv = query_h @ W_in_h^T + b (single bf16 product), BK=64,
// global_load_lds staging with both-sides XOR swizzle (main loop unchanged).
// Epilogue v3 (R12 bugfix): per-branch staging.
//  - q/k tiles: SH[m*142 + c]; read-back thread=(m, head-half), 8x 16B stores.
//  - v tiles:   SH[c*142 + m] (transposed; stride 142 = 71 dwords odd ->
//    conflict-free writes AND reads); read-back thread=(c, m-half),
//    16x 8B stores. Values bit-identical to R11.
// ---------------------------------------------------------------------------
__global__ __launch_bounds__(256) void gemm_bf16_qkv(const ushortT* __restrict__ Ah,
                                                     const ushortT* __restrict__ Bh,
                                                     const float* __restrict__ bias,
                                                     ushortT* __restrict__ qh_o,
                                                     ushortT* __restrict__ kh_o,
                                                     ushortT* __restrict__ vt_o)
{
    const int K = E_C;
    __shared__ ushortT SH[18176];    // main loop: As=[0:8192) Bs=[8192:16384); epilogue: 128x142

    const int tid = threadIdx.x;
    const int bm = blockIdx.y * 128, bn = blockIdx.x * 128;
    const int w  = tid >> 6;
    const int wm = w >> 1, wn = w & 1;
    const int l  = tid & 63;
    const int lc = l & 31, hi = l >> 5;

    f32x16 acc[2][2];
    #pragma unroll
    for (int a = 0; a < 2; a++)
        #pragma unroll
        for (int b = 0; b < 2; b++)
            #pragma unroll
            for (int r = 0; r < 16; r++) acc[a][b][r] = 0.f;

    for (int k0 = 0; k0 < K; k0 += 64) {
        #pragma unroll
        for (int it = 0; it < 4; it++) {
            int idx = it * 256 + (w << 6) + l;      // 16B-unit index, 0..1023
            int row = idx >> 3;
            int cs  = (idx & 7) ^ (row & 7);        // pre-swizzled source col
            size_t goff = (size_t)row * K + k0 + cs * 8;
            int lbase = (it * 256 + (w << 6)) * 8;  // wave-uniform, ushorts
            gload_lds16(Ah + (size_t)bm * K + goff, SH + lbase);
            gload_lds16(Bh + (size_t)bn * K + goff, SH + 8192 + lbase);
        }
        __syncthreads();

        #pragma unroll
        for (int ks = 0; ks < 4; ks++) {
            bf16x8 af[2], bfr[2];
            #pragma unroll
            for (int ms = 0; ms < 2; ms++) {
                int r = wm * 64 + ms * 32 + lc;
                af[ms] = *(const bf16x8*)(&SH[r * 64 + ((((ks << 1) + hi) ^ (r & 7)) << 3)]);
            }
            #pragma unroll
            for (int ns = 0; ns < 2; ns++) {
                int r = wn * 64 + ns * 32 + lc;
                bfr[ns] = *(const bf16x8*)(&SH[8192 + r * 64 + ((((ks << 1) + hi) ^ (r & 7)) << 3)]);
            }
            #pragma unroll
            for (int ms = 0; ms < 2; ms++)
                #pragma unroll
                for (int ns = 0; ns < 2; ns++)
                    acc[ms][ns] = mfma_bf16(af[ms], bfr[ns], acc[ms][ns]);
        }
        __syncthreads();
    }

    if (bn >= 2048) {
        // ---- V: stage TRANSPOSED SH[c*142 + m] (CF both sides) ----
        #pragma unroll
        for (int ms = 0; ms < 2; ms++)
            #pragma unroll
            for (int ns = 0; ns < 2; ns++) {
                int c = wn * 64 + ns * 32 + lc;
                float bcol = bias[bn + c];
                #pragma unroll
                for (int r = 0; r < 16; r++) {
                    int m = wm * 64 + ms * 32 + (r & 3) + 8 * (r >> 2) + 4 * hi;
                    SH[c * 142 + m] = f2bf(acc[ms][ns][r] + bcol);
                }
            }
        __syncthreads();
        // v_t [n][d][t]: thread = (c = tid>>1, m-half); 16x 8B stores
        int c    = tid >> 1;          // 0..127 (col within block)
        int half = tid & 1;
        int dd = c & 63;
        int hh = ((bn - 2048) >> 6) + (c >> 6);
        size_t tb = (size_t)(bm >> 1) + 32 * half;
        ushortT* d0 = vt_o + ((size_t)(hh)       * 64 + dd) * T_LEN + tb;  // b=0
        ushortT* d1 = vt_o + ((size_t)(H_C + hh) * 64 + dd) * T_LEN + tb;  // b=1
        const ushortT* srow = SH + c * 142 + 64 * half;
        #pragma unroll
        for (int k = 0; k < 8; k++) {
            ushort4v e0, e1;
            #pragma unroll
            for (int jj = 0; jj < 4; jj++) {
                e0[jj] = srow[8 * k + 2 * jj];       // m even -> b=0
                e1[jj] = srow[8 * k + 2 * jj + 1];   // m odd  -> b=1
            }
            *(ushort4v*)(d0 + 4 * k) = e0;
            *(ushort4v*)(d1 + 4 * k) = e1;
        }
    } else {
        // ---- Q/K: stage SH[m*142 + c] ----
        #pragma unroll
        for (int ms = 0; ms < 2; ms++)
            #pragma unroll
            for (int ns = 0; ns < 2; ns++) {
                int c = wn * 64 + ns * 32 + lc;
                float bcol = bias[bn + c];
                #pragma unroll
                for (int r = 0; r < 16; r++) {
                    int m = wm * 64 + ms * 32 + (r & 3) + 8 * (r >> 2) + 4 * hi;
                    SH[m * 142 + c] = f2bf(acc[ms][ns][r] + bcol);
                }
            }
        __syncthreads();
        // q_h / k_h [n][t][d]: thread = (m = tid>>1, head-half); 8x 16B stores
        int m    = tid >> 1;          // 0..127 (row within block)
        int half = tid & 1;           // head within block
        ushortT* base = (bn < 1024) ? qh_o : kh_o;
        int hh = ((bn & 1023) >> 6) + half;
        int bb = m & 1;
        int t  = (bm >> 1) + (m >> 1);
        ushortT* drow = base + ((size_t)(bb * H_C + hh) * T_LEN + t) * 64;
        const ushortT* srow = SH + m * 142 + 64 * half;
        #pragma unroll
        for (int k = 0; k < 8; k++) {
            ushort8v e;
            #pragma unroll
            for (int jj = 0; jj < 4; jj++) {
                ushort2v p = *(const ushort2v*)(srow + 8 * k + 2 * jj);
                e[2 * jj]     = p.x;
                e[2 * jj + 1] = p.y;
            }
            *(ushort8v*)(drow + 8 * k) = e;
        }
    }
}

// ---------------------------------------------------------------------------
// gemm_bf16_out: out = a_hi @ Woh^T + b_out, f32 nontemporal out. BK=64.
// ---------------------------------------------------------------------------
__global__ __launch_bounds__(256) void gemm_bf16_out(const ushortT* __restrict__ Ah,
                                                     const ushortT* __restrict__ Bh,
                                                     const float* __restrict__ bias,
                                                     float* __restrict__ Cf)
{
    const int K = E_C, N = E_C;
    __shared__ ushortT As[128][64];
    __shared__ ushortT Bs[128][64];

    const int tid = threadIdx.x;
    const int bm = blockIdx.y * 128, bn = blockIdx.x * 128;
    const int w  = tid >> 6;
    const int wm = w >> 1, wn = w & 1;
    const int l  = tid & 63;
    const int lc = l & 31, hi = l >> 5;

    f32x16 acc[2][2];
    #pragma unroll
    for (int a = 0; a < 2; a++)
        #pragma unroll
        for (int b = 0; b < 2; b++)
            #pragma unroll
            for (int r = 0; r < 16; r++) acc[a][b][r] = 0.f;

    for (int k0 = 0; k0 < K; k0 += 64) {
        #pragma unroll
        for (int it = 0; it < 4; it++) {
            int idx = it * 256 + (w << 6) + l;
            int row = idx >> 3;
            int cs  = (idx & 7) ^ (row & 7);
            size_t goff = (size_t)row * K + k0 + cs * 8;
            int lbase = (it * 256 + (w << 6)) * 8;
            gload_lds16(Ah + (size_t)bm * K + goff, &As[0][0] + lbase);
            gload_lds16(Bh + (size_t)bn * K + goff, &Bs[0][0] + lbase);
        }
        __syncthreads();

        #pragma unroll
        for (int ks = 0; ks < 4; ks++) {
            bf16x8 af[2], bfr[2];
            #pragma unroll
            for (int ms = 0; ms < 2; ms++) {
                int r = wm * 64 + ms * 32 + lc;
                af[ms] = *(const bf16x8*)(&As[r][(((ks << 1) + hi) ^ (r & 7)) << 3]);
            }
            #pragma unroll
            for (int ns = 0; ns < 2; ns++) {
                int r = wn * 64 + ns * 32 + lc;
                bfr[ns] = *(const bf16x8*)(&Bs[r][(((ks << 1) + hi) ^ (r & 7)) << 3]);
            }
            #pragma unroll
            for (int ms = 0; ms < 2; ms++)
                #pragma unroll
                for (int ns = 0; ns < 2; ns++)
                    acc[ms][ns] = mfma_bf16(af[ms], bfr[ns], acc[ms][ns]);
        }
        __syncthreads();
    }

    #pragma unroll
    for (int ms = 0; ms < 2; ms++)
        #pragma unroll
        for (int ns = 0; ns < 2; ns++)
            #pragma unroll
            for (int r = 0; r < 16; r++) {
                int row = bm + wm * 64 + ms * 32 + (r & 3) + 8 * (r >> 2) + 4 * hi;
                int col = bn + wn * 64 + ns * 32 + lc;
                __builtin_nontemporal_store(acc[ms][ns][r] + bias[col],
                                            &Cf[(size_t)row * N + col]);
            }
}

// ---------------------------------------------------------------------------
// attn_mfma (unchanged): block = (head n, 128 q-rows), 256 threads = 4 waves,
// wave-private, zero barriers; 2-pass, exp2-folded, nt p_out stores.
// ---------------------------------------------------------------------------
__global__ __launch_bounds__(256) void attn_mfma(const ushortT* __restrict__ q_h,
                                                 const ushortT* __restrict__ k_h,
                                                 const ushortT* __restrict__ v_t,
                                                 float* __restrict__ p_out,
                                                 ushortT* __restrict__ a_hi)
{
    __shared__ ushortT plds[4][32][64];   // per-wave P tile, XOR-swizzled

    const int n = blockIdx.x;
    const int b = n >> 4, h = n & 15;
    const int t0 = blockIdx.y * 128;
    const int tid = threadIdx.x;
    const int w = tid >> 6, l = tid & 63;
    const int lc = l & 31, hi = l >> 5;
    const int trow_base = t0 + w * 32;

    const ushortT* qb = q_h + ((size_t)n * T_LEN + trow_base) * 64;
    const ushortT* kb = k_h + (size_t)n * T_LEN * 64;
    const ushortT* vb = v_t + (size_t)n * 64 * T_LEN;

    bf16x8 qf[4];
    #pragma unroll
    for (int ks = 0; ks < 4; ks++)
        qf[ks] = *(const bf16x8*)(qb + (size_t)lc * 64 + ks * 16 + hi * 8);

    const float K2 = 0.18033688011112042f;   // (1/8) * log2(e)

    // ---- pass A: row sums ----
    float sum[16];
    #pragma unroll
    for (int r = 0; r < 16; r++) sum[r] = 0.f;

    for (int s0 = 0; s0 < T_LEN; s0 += 32) {
        const ushortT* kr = kb + (size_t)(s0 + lc) * 64 + hi * 8;
        f32x16 c;
        #pragma unroll
        for (int r = 0; r < 16; r++) c[r] = 0.f;
        #pragma unroll
        for (int ks = 0; ks < 4; ks++)
            c = mfma_bf16(qf[ks], *(const bf16x8*)(kr + ks * 16), c);
        #pragma unroll
        for (int r = 0; r < 16; r++) sum[r] += __builtin_amdgcn_exp2f(c[r] * K2);
    }
    #pragma unroll
    for (int r = 0; r < 16; r++) {
        float s = sum[r];
        s += __shfl_xor(s, 1, 64);
        s += __shfl_xor(s, 2, 64);
        s += __shfl_xor(s, 4, 64);
        s += __shfl_xor(s, 8, 64);
        s += __shfl_xor(s, 16, 64);
        sum[r] = 1.0f / s;    // inv
    }

    // ---- pass B ----
    f32x16 o0, o1;
    #pragma unroll
    for (int r = 0; r < 16; r++) { o0[r] = 0.f; o1[r] = 0.f; }
    char* plbase = (char*)&plds[w][0][0];

    for (int s0 = 0; s0 < T_LEN; s0 += 32) {
        const ushortT* kr = kb + (size_t)(s0 + lc) * 64 + hi * 8;
        f32x16 c;
        #pragma unroll
        for (int r = 0; r < 16; r++) c[r] = 0.f;
        #pragma unroll
        for (int ks = 0; ks < 4; ks++)
            c = mfma_bf16(qf[ks], *(const bf16x8*)(kr + ks * 16), c);

        float pv[16];
        #pragma unroll
        for (int r = 0; r < 16; r++) pv[r] = __builtin_amdgcn_exp2f(c[r] * K2) * sum[r];

        size_t pbase = ((size_t)n * T_LEN) * T_LEN + s0 + lc;
        #pragma unroll
        for (int r = 0; r < 16; r++) {
            int t = trow_base + (r & 3) + 8 * (r >> 2) + 4 * hi;
            __builtin_nontemporal_store(pv[r], &p_out[pbase + (size_t)t * T_LEN]);
        }
        #pragma unroll
        for (int r = 0; r < 16; r++) {
            int row = (r & 3) + 8 * (r >> 2) + 4 * hi;
            int byte = row * 128 + ((lc * 2) ^ ((row & 7) << 4));
            *(ushortT*)(plbase + byte) = f2bf(pv[r]);
        }
        bf16x8 pa[2];
        #pragma unroll
        for (int sh = 0; sh < 2; sh++) {
            int S = (hi * 8 + sh * 16) * 2;
            int byte = lc * 128 + (S ^ ((lc & 7) << 4));
            pa[sh] = *(const bf16x8*)(plbase + byte);
        }
        #pragma unroll
        for (int sh = 0; sh < 2; sh++) {
            bf16x8 v0 = *(const bf16x8*)(vb + (size_t)(lc) * T_LEN + s0 + sh * 16 + hi * 8);
            bf16x8 v1 = *(const bf16x8*)(vb + (size_t)(32 + lc) * T_LEN + s0 + sh * 16 + hi * 8);
            o0 = mfma_bf16(pa[sh], v0, o0);
            o1 = mfma_bf16(pa[sh], v1, o1);
        }
    }

    // ---- write attn bf16 (already normalized; fed to out-projection) ----
    #pragma unroll
    for (int r = 0; r < 16; r++) {
        int t = trow_base + (r & 3) + 8 * (r >> 2) + 4 * hi;
        size_t m = (size_t)t * BSZ_C + b;
        size_t base = m * 1024 + h * 64;
        a_hi[base + lc]      = f2bf(o0[r]);
        a_hi[base + 32 + lc] = f2bf(o1[r]);
    }
}

// ---------------------------------------------------------------------------
extern "C" void kernel_launch(void* const* d_in, const int* in_sizes, int n_in,
                              void* d_out, int out_size, void* d_ws, size_t ws_size,
                              hipStream_t stream) {
    const float* query = (const float*)d_in[0];
    // d_in[1]/d_in[2] unused (reference derives q,k,v all from `query`)
    const float* W_in  = (const float*)d_in[3];
    const float* b_in  = (const float*)d_in[4];
    const float* W_out = (const float*)d_in[5];
    const float* b_out = (const float*)d_in[6];

    float* out   = (float*)d_out;
    float* p_out = out + (size_t)T_LEN * BSZ_C * E_C;

    char* ws = (char*)d_ws;
    ushortT* qh   = (ushortT*)(ws + 0);          // 8 MiB  query bf16
    ushortT* Wih  = (ushortT*)(ws + 8388608);    // 6 MiB  W_in bf16
    ushortT* Woh  = (ushortT*)(ws + 14680064);   // 2 MiB  W_out bf16
    ushortT* q_h  = (ushortT*)(ws + 16777216);   // 8 MiB
    ushortT* k_h  = (ushortT*)(ws + 25165824);   // 8 MiB
    ushortT* v_t  = (ushortT*)(ws + 33554432);   // 8 MiB
    ushortT* a_hi = (ushortT*)(ws + 41943040);   // 8 MiB (end 50331648)

    pack3<<<dim3(2048), dim3(256), 0, stream>>>(query, W_in, W_out, qh, Wih, Woh);

    gemm_bf16_qkv<<<dim3(E3 / 128, M_C / 128), dim3(256), 0, stream>>>(
        qh, Wih, b_in, q_h, k_h, v_t);

    attn_mfma<<<dim3(NH, T_LEN / 128), dim3(256), 0, stream>>>(
        q_h, k_h, v_t, p_out, a_hi);

    gemm_bf16_out<<<dim3(E_C / 128, M_C / 128), dim3(256), 0, stream>>>(
        a_hi, Woh, b_out, out);
}